// Round 2
// baseline (233.432 us; speedup 1.0000x reference)
//
#include <hip/hip_runtime.h>
#include <cstdint>
#include <cstddef>

#define B_   4
#define T_   2048
#define D_   1024
#define H_   8
#define DK_  64
#define HD_  512      // H*DK
#define CH_  64       // chunk length
#define NC_  32       // T_/CH_
#define EPS_ 1e-6f

typedef __attribute__((ext_vector_type(4))) float f32x4;
typedef __attribute__((ext_vector_type(8))) short s16x8;

__device__ __forceinline__ unsigned short f2bf(float f) {
    unsigned int x = __float_as_uint(f);
    unsigned int r = (x + 0x7FFFu + ((x >> 16) & 1u)) >> 16;
    return (unsigned short)r;
}
__device__ __forceinline__ float bf2f(unsigned short u) {
    return __uint_as_float(((unsigned int)u) << 16);
}
__device__ __forceinline__ void ld4(const float* p, float* o) {
    float4 v = *(const float4*)p; o[0]=v.x; o[1]=v.y; o[2]=v.z; o[3]=v.w;
}

// ---------------- K0: fp32 -> bf16 convert (vectorized x4) ----------------
__global__ void k_f32_to_bf16(const float* __restrict__ in, unsigned short* __restrict__ out, int n4) {
    int i = blockIdx.x * blockDim.x + threadIdx.x;
    if (i < n4) {
        float4 v = ((const float4*)in)[i];
        ushort4 o;
        o.x = f2bf(v.x); o.y = f2bf(v.y); o.z = f2bf(v.z); o.w = f2bf(v.w);
        ((ushort4*)out)[i] = o;
    }
}

// ---------------- K1: fused QKVG GEMM, bf16 MFMA, C = X @ W^T ----------------
// grid: (16, 64). blockIdx.x: [0..3]->Q tiles, [4..7]->K, [8..11]->V, [12..15]->G
#define GT_M 128
#define GT_N 128
#define GBK  64
#define LDA  72   // LDS row stride (bf16 units): 144B = 9x16B, breaks pow2 conflicts

__global__ __launch_bounds__(256) void k_gemm_qkvg(
    const unsigned short* __restrict__ xb,
    const unsigned short* __restrict__ wqb, const unsigned short* __restrict__ wkb,
    const unsigned short* __restrict__ wvb, const unsigned short* __restrict__ wgb,
    const float* __restrict__ bias,
    unsigned short* __restrict__ qo, unsigned short* __restrict__ ko,
    unsigned short* __restrict__ vo, unsigned short* __restrict__ go)
{
    __shared__ unsigned short As[GT_M * LDA];
    __shared__ unsigned short Bs[GT_N * LDA];
    const int tid = threadIdx.x;
    const int which = blockIdx.x >> 2;           // 0=Q 1=K 2=V 3=G
    const int nb    = blockIdx.x & 3;
    const int m0    = blockIdx.y * GT_M;
    const int n0    = nb * GT_N;                 // within [0,512)
    const unsigned short* Wp = (which == 0) ? wqb : (which == 1) ? wkb : (which == 2) ? wvb : wgb;
    unsigned short* Op       = (which == 0) ? qo  : (which == 1) ? ko  : (which == 2) ? vo  : go;
    const int K = D_;

    const int lane = tid & 63, wave = tid >> 6;
    const int wm = (wave >> 1) * 64, wn = (wave & 1) * 64;
    const int r16 = lane & 15, quad = lane >> 4;

    f32x4 acc[4][4];
    #pragma unroll
    for (int a = 0; a < 4; a++)
        #pragma unroll
        for (int b = 0; b < 4; b++) acc[a][b] = 0.0f;

    for (int ko_ = 0; ko_ < K; ko_ += GBK) {
        #pragma unroll
        for (int i = 0; i < 4; i++) {
            int id = i * 256 + tid;          // 0..1023
            int row = id >> 3, seg = id & 7; // 128 rows x 8 segs of 8 bf16
            *(uint4*)&As[row * LDA + seg * 8] =
                *(const uint4*)(xb + (size_t)(m0 + row) * K + ko_ + seg * 8);
            *(uint4*)&Bs[row * LDA + seg * 8] =
                *(const uint4*)(Wp + (size_t)(n0 + row) * K + ko_ + seg * 8);
        }
        __syncthreads();
        #pragma unroll
        for (int kk = 0; kk < GBK; kk += 32) {
            s16x8 af[4], bf[4];
            #pragma unroll
            for (int mt = 0; mt < 4; mt++)
                af[mt] = *(const s16x8*)&As[(wm + mt * 16 + r16) * LDA + kk + quad * 8];
            #pragma unroll
            for (int nt = 0; nt < 4; nt++)
                bf[nt] = *(const s16x8*)&Bs[(wn + nt * 16 + r16) * LDA + kk + quad * 8];
            #pragma unroll
            for (int mt = 0; mt < 4; mt++)
                #pragma unroll
                for (int nt = 0; nt < 4; nt++)
                    acc[mt][nt] = __builtin_amdgcn_mfma_f32_16x16x32_bf16(af[mt], bf[nt], acc[mt][nt], 0, 0, 0);
        }
        __syncthreads();
    }
    #pragma unroll
    for (int mt = 0; mt < 4; mt++) {
        #pragma unroll
        for (int nt = 0; nt < 4; nt++) {
            int col = n0 + wn + nt * 16 + r16;
            float bv = (which == 3) ? bias[col] : 0.0f;
            #pragma unroll
            for (int r = 0; r < 4; r++) {
                int row = m0 + wm + mt * 16 + quad * 4 + r;
                float v = acc[mt][nt][r];
                if (which <= 1)      v = (v > 0.0f) ? v + 1.0f : __builtin_expf(v);     // phi = elu+1
                else if (which == 3) v = 1.0f / (1.0f + __builtin_expf(-(v + bv)));     // sigmoid gate
                Op[(size_t)row * HD_ + col] = f2bf(v);
            }
        }
    }
}

// ---------------- K5: output GEMM: Y = OG @ W_O^T (fp32 out) ----------------
__global__ __launch_bounds__(256) void k_gemm_out(
    const unsigned short* __restrict__ ogb, const unsigned short* __restrict__ wob,
    float* __restrict__ y)
{
    __shared__ unsigned short As[GT_M * LDA];
    __shared__ unsigned short Bs[GT_N * LDA];
    const int tid = threadIdx.x;
    const int m0 = blockIdx.y * GT_M;
    const int n0 = blockIdx.x * GT_N;
    const int K = HD_;   // 512

    const int lane = tid & 63, wave = tid >> 6;
    const int wm = (wave >> 1) * 64, wn = (wave & 1) * 64;
    const int r16 = lane & 15, quad = lane >> 4;

    f32x4 acc[4][4];
    #pragma unroll
    for (int a = 0; a < 4; a++)
        #pragma unroll
        for (int b = 0; b < 4; b++) acc[a][b] = 0.0f;

    for (int ko_ = 0; ko_ < K; ko_ += GBK) {
        #pragma unroll
        for (int i = 0; i < 4; i++) {
            int id = i * 256 + tid;
            int row = id >> 3, seg = id & 7;
            *(uint4*)&As[row * LDA + seg * 8] =
                *(const uint4*)(ogb + (size_t)(m0 + row) * K + ko_ + seg * 8);
            *(uint4*)&Bs[row * LDA + seg * 8] =
                *(const uint4*)(wob + (size_t)(n0 + row) * K + ko_ + seg * 8);
        }
        __syncthreads();
        #pragma unroll
        for (int kk = 0; kk < GBK; kk += 32) {
            s16x8 af[4], bf[4];
            #pragma unroll
            for (int mt = 0; mt < 4; mt++)
                af[mt] = *(const s16x8*)&As[(wm + mt * 16 + r16) * LDA + kk + quad * 8];
            #pragma unroll
            for (int nt = 0; nt < 4; nt++)
                bf[nt] = *(const s16x8*)&Bs[(wn + nt * 16 + r16) * LDA + kk + quad * 8];
            #pragma unroll
            for (int mt = 0; mt < 4; mt++)
                #pragma unroll
                for (int nt = 0; nt < 4; nt++)
                    acc[mt][nt] = __builtin_amdgcn_mfma_f32_16x16x32_bf16(af[mt], bf[nt], acc[mt][nt], 0, 0, 0);
        }
        __syncthreads();
    }
    #pragma unroll
    for (int mt = 0; mt < 4; mt++)
        #pragma unroll
        for (int nt = 0; nt < 4; nt++) {
            int col = n0 + wn + nt * 16 + r16;
            #pragma unroll
            for (int r = 0; r < 4; r++) {
                int row = m0 + wm + mt * 16 + quad * 4 + r;
                y[(size_t)row * D_ + col] = acc[mt][nt][r];
            }
        }
}

// ---------------- K2: per-chunk decayed sums ----------------
// Ssum[bh,c][i][j] = sum_l gamma^(CH-1-l) k_l[i] v_l[j];  zsum likewise.
__global__ __launch_bounds__(256) void k_chunk_sums(
    const unsigned short* __restrict__ Kb, const unsigned short* __restrict__ Vb,
    float* __restrict__ Ssum, float* __restrict__ zsum, const float* __restrict__ decay_log)
{
    __shared__ float kl[CH_ * 68];
    __shared__ float vl[CH_ * 68];
    const int tid = threadIdx.x;
    const int bc  = blockIdx.x;            // bh*NC_ + c
    const int c   = bc & (NC_ - 1);
    const int bh  = bc >> 5;
    const int h   = bh & (H_ - 1);
    const int b   = bh >> 3;
    const float g  = 1.0f / (1.0f + __builtin_expf(-decay_log[h]));
    const float lg = __builtin_log2f(g);
    const int t0 = c * CH_;

    #pragma unroll
    for (int e = 0; e < 2; e++) {
        int lid = e * 256 + tid;           // 0..511 : 64 rows x 8 segs
        int l = lid >> 3, d0 = (lid & 7) * 8;
        float w = __builtin_exp2f((float)(CH_ - 1 - l) * lg);
        size_t gidx = (size_t)(b * T_ + t0 + l) * HD_ + h * DK_ + d0;
        uint4 kraw = *(const uint4*)(Kb + gidx);
        uint4 vraw = *(const uint4*)(Vb + gidx);
        const unsigned short* kp = (const unsigned short*)&kraw;
        const unsigned short* vp = (const unsigned short*)&vraw;
        #pragma unroll
        for (int j = 0; j < 8; j++) {
            kl[l * 68 + d0 + j] = bf2f(kp[j]) * w;   // decay folded into k
            vl[l * 68 + d0 + j] = bf2f(vp[j]);
        }
    }
    __syncthreads();

    const int ti = tid >> 4, tj = tid & 15;
    const int i0 = ti * 4, j0 = tj * 4;
    float acc[4][4];
    #pragma unroll
    for (int r = 0; r < 4; r++)
        #pragma unroll
        for (int cc = 0; cc < 4; cc++) acc[r][cc] = 0.0f;

    for (int l = 0; l < CH_; l++) {
        float kv[4], vv[4];
        ld4(&kl[l * 68 + i0], kv);
        ld4(&vl[l * 68 + j0], vv);
        #pragma unroll
        for (int r = 0; r < 4; r++)
            #pragma unroll
            for (int cc = 0; cc < 4; cc++) acc[r][cc] += kv[r] * vv[cc];
    }
    size_t base = (size_t)bc * (DK_ * DK_);
    #pragma unroll
    for (int r = 0; r < 4; r++) {
        float4 st = make_float4(acc[r][0], acc[r][1], acc[r][2], acc[r][3]);
        *(float4*)&Ssum[base + (size_t)(i0 + r) * DK_ + j0] = st;
    }
    if (tid < DK_) {
        float s = 0.0f;
        for (int l = 0; l < CH_; l++) s += kl[l * 68 + tid];
        zsum[(size_t)bc * DK_ + tid] = s;
    }
}

// ---------------- K3: exclusive cross-chunk scan (in place) ----------------
__global__ __launch_bounds__(128) void k_chunk_scan(
    float* __restrict__ Ssum, float* __restrict__ zsum, const float* __restrict__ decay_log)
{
    const int tid = threadIdx.x;
    const int grp = blockIdx.x & 31;
    const int bh  = blockIdx.x >> 5;
    const int h   = bh & (H_ - 1);
    const float g  = 1.0f / (1.0f + __builtin_expf(-decay_log[h]));
    const float gC = __builtin_exp2f((float)CH_ * __builtin_log2f(g));   // gamma^CH
    int elem = grp * 128 + tid;                          // 0..4095
    float s = 0.0f;
    for (int c = 0; c < NC_; c++) {
        size_t idx = ((size_t)(bh * NC_ + c)) * 4096 + elem;
        float v = Ssum[idx];
        Ssum[idx] = s;              // exclusive prefix: state BEFORE chunk c
        s = gC * s + v;
    }
    if (grp == 0 && tid < DK_) {
        float z = 0.0f;
        for (int c = 0; c < NC_; c++) {
            size_t idx = ((size_t)(bh * NC_ + c)) * DK_ + tid;
            float v = zsum[idx];
            zsum[idx] = z;
            z = gC * z + v;
        }
    }
}

// ---------------- K4: per-chunk outputs (intra attention + carried state) ----------------
__global__ __launch_bounds__(256) void k_chunk_out(
    const unsigned short* __restrict__ Qb, const unsigned short* __restrict__ Kb,
    const unsigned short* __restrict__ Vb, const unsigned short* __restrict__ Gb,
    const float* __restrict__ Ssum, const float* __restrict__ zsum,
    unsigned short* __restrict__ OGb, const float* __restrict__ decay_log)
{
    __shared__ float BufA[CH_ * 68];   // qT, later scT
    __shared__ float BufB[CH_ * 68];   // kT, later v
    __shared__ float BufC[CH_ * 68];   // S_prev (rows = k-dim, cols = v-dim)
    __shared__ float den_l[CH_];
    __shared__ float zp_l[DK_];
    __shared__ float gpow[CH_ + 1];

    const int tid = threadIdx.x;
    const int bc  = blockIdx.x;
    const int c   = bc & (NC_ - 1);
    const int bh  = bc >> 5;
    const int h   = bh & (H_ - 1);
    const int b   = bh >> 3;
    const float g  = 1.0f / (1.0f + __builtin_expf(-decay_log[h]));
    const float lg = __builtin_log2f(g);
    const int t0 = c * CH_;

    if (tid <= CH_) gpow[tid] = __builtin_exp2f((float)tid * lg);
    if (tid < DK_)  zp_l[tid] = zsum[(size_t)bc * DK_ + tid];

    // load q,k transposed: Buf[d][l]
    #pragma unroll
    for (int e = 0; e < 2; e++) {
        int lid = e * 256 + tid;
        int l = lid >> 3, d0 = (lid & 7) * 8;
        size_t gidx = (size_t)(b * T_ + t0 + l) * HD_ + h * DK_ + d0;
        uint4 qraw = *(const uint4*)(Qb + gidx);
        uint4 kraw = *(const uint4*)(Kb + gidx);
        const unsigned short* qp = (const unsigned short*)&qraw;
        const unsigned short* kp = (const unsigned short*)&kraw;
        #pragma unroll
        for (int j = 0; j < 8; j++) {
            BufA[(d0 + j) * 68 + l] = bf2f(qp[j]);
            BufB[(d0 + j) * 68 + l] = bf2f(kp[j]);
        }
    }
    {   // load S_prev natural layout
        size_t base = (size_t)bc * 4096;
        #pragma unroll
        for (int e = 0; e < 4; e++) {
            int flat = (e * 256 + tid) * 4;
            int row = flat >> 6, c0 = flat & 63;
            *(float4*)&BufC[row * 68 + c0] = *(const float4*)&Ssum[base + flat];
        }
    }
    __syncthreads();

    const int ti = tid >> 4, tj = tid & 15;
    const int i0 = ti * 4, j0 = tj * 4;
    float sc[4][4], it[4][4];
    #pragma unroll
    for (int r = 0; r < 4; r++)
        #pragma unroll
        for (int cc = 0; cc < 4; cc++) { sc[r][cc] = 0.0f; it[r][cc] = 0.0f; }

    for (int d = 0; d < DK_; d++) {
        float qv[4], kv[4], sv[4];
        ld4(&BufA[d * 68 + i0], qv);
        ld4(&BufB[d * 68 + j0], kv);
        ld4(&BufC[d * 68 + j0], sv);
        #pragma unroll
        for (int r = 0; r < 4; r++)
            #pragma unroll
            for (int cc = 0; cc < 4; cc++) {
                sc[r][cc] += qv[r] * kv[cc];
                it[r][cc] += qv[r] * sv[cc];
            }
    }
    // decay weights, causal mask, row sums for denominator
    #pragma unroll
    for (int r = 0; r < 4; r++) {
        int i = i0 + r;
        #pragma unroll
        for (int cc = 0; cc < 4; cc++) {
            int jl = j0 + cc;
            sc[r][cc] = (jl <= i) ? sc[r][cc] * gpow[i - jl] : 0.0f;
            it[r][cc] *= gpow[i + 1];
        }
        float rs = sc[r][0] + sc[r][1] + sc[r][2] + sc[r][3];
        rs += __shfl_xor(rs, 1);
        rs += __shfl_xor(rs, 2);
        rs += __shfl_xor(rs, 4);
        rs += __shfl_xor(rs, 8);
        if (tj == 0) den_l[i] = rs;   // intra part
    }
    __syncthreads();
    if (tid < DK_) {                  // + gamma^(i+1) * q_i . z_prev + eps
        float dp = 0.0f;
        for (int d = 0; d < DK_; d++) dp += BufA[d * 68 + tid] * zp_l[d];
        den_l[tid] += gpow[tid + 1] * dp + EPS_;
    }
    __syncthreads();
    // write scT into BufA; load v into BufB
    #pragma unroll
    for (int cc = 0; cc < 4; cc++) {
        float4 st = make_float4(sc[0][cc], sc[1][cc], sc[2][cc], sc[3][cc]);
        *(float4*)&BufA[(j0 + cc) * 68 + i0] = st;
    }
    #pragma unroll
    for (int e = 0; e < 2; e++) {
        int lid = e * 256 + tid;
        int l = lid >> 3, d0 = (lid & 7) * 8;
        size_t gidx = (size_t)(b * T_ + t0 + l) * HD_ + h * DK_ + d0;
        uint4 vraw = *(const uint4*)(Vb + gidx);
        const unsigned short* vp = (const unsigned short*)&vraw;
        #pragma unroll
        for (int j = 0; j < 8; j++) BufB[l * 68 + d0 + j] = bf2f(vp[j]);
    }
    __syncthreads();

    float og[4][4];
    #pragma unroll
    for (int r = 0; r < 4; r++)
        #pragma unroll
        for (int cc = 0; cc < 4; cc++) og[r][cc] = it[r][cc];

    for (int jl = 0; jl < CH_; jl++) {
        float scv[4], vv[4];
        ld4(&BufA[jl * 68 + i0], scv);
        ld4(&BufB[jl * 68 + j0], vv);
        #pragma unroll
        for (int r = 0; r < 4; r++)
            #pragma unroll
            for (int cc = 0; cc < 4; cc++) og[r][cc] += scv[r] * vv[cc];
    }
    #pragma unroll
    for (int r = 0; r < 4; r++) {
        int i = i0 + r;
        float rcp = 1.0f / den_l[i];
        size_t gidx = (size_t)(b * T_ + t0 + i) * HD_ + h * DK_ + j0;
        ushort4 graw = *(const ushort4*)(Gb + gidx);
        ushort4 o;
        o.x = f2bf(og[r][0] * rcp * bf2f(graw.x));
        o.y = f2bf(og[r][1] * rcp * bf2f(graw.y));
        o.z = f2bf(og[r][2] * rcp * bf2f(graw.z));
        o.w = f2bf(og[r][3] * rcp * bf2f(graw.w));
        *(ushort4*)(OGb + gidx) = o;
    }
}

// ---------------- host ----------------
extern "C" void kernel_launch(void* const* d_in, const int* in_sizes, int n_in,
                              void* d_out, int out_size, void* d_ws, size_t ws_size,
                              hipStream_t stream)
{
    (void)in_sizes; (void)n_in; (void)out_size; (void)ws_size;
    const float* x         = (const float*)d_in[0];
    const float* W_Q       = (const float*)d_in[1];
    const float* W_K       = (const float*)d_in[2];
    const float* W_V       = (const float*)d_in[3];
    const float* W_gw      = (const float*)d_in[4];
    const float* W_gb      = (const float*)d_in[5];
    const float* W_O       = (const float*)d_in[6];
    const float* decay_log = (const float*)d_in[7];
    float* y = (float*)d_out;

    char* ws = (char*)d_ws;
    size_t off = 0;
    auto alloc = [&](size_t bytes) { void* p = ws + off; off += (bytes + 255) & ~(size_t)255; return p; };
    unsigned short* xb   = (unsigned short*)alloc((size_t)B_ * T_ * D_ * 2);
    unsigned short* wqb  = (unsigned short*)alloc((size_t)HD_ * D_ * 2);
    unsigned short* wkb  = (unsigned short*)alloc((size_t)HD_ * D_ * 2);
    unsigned short* wvb  = (unsigned short*)alloc((size_t)HD_ * D_ * 2);
    unsigned short* wgb  = (unsigned short*)alloc((size_t)HD_ * D_ * 2);
    unsigned short* wob  = (unsigned short*)alloc((size_t)D_ * HD_ * 2);
    unsigned short* qb   = (unsigned short*)alloc((size_t)B_ * T_ * HD_ * 2);
    unsigned short* kb   = (unsigned short*)alloc((size_t)B_ * T_ * HD_ * 2);
    unsigned short* vb   = (unsigned short*)alloc((size_t)B_ * T_ * HD_ * 2);
    unsigned short* gb   = (unsigned short*)alloc((size_t)B_ * T_ * HD_ * 2);
    unsigned short* ogb  = (unsigned short*)alloc((size_t)B_ * T_ * HD_ * 2);
    float* Ssum = (float*)alloc((size_t)B_ * H_ * NC_ * DK_ * DK_ * 4);
    float* zsum = (float*)alloc((size_t)B_ * H_ * NC_ * DK_ * 4);

    int n4;
    n4 = B_ * T_ * D_ / 4;
    k_f32_to_bf16<<<(n4 + 255) / 256, 256, 0, stream>>>(x, xb, n4);
    n4 = HD_ * D_ / 4;
    k_f32_to_bf16<<<(n4 + 255) / 256, 256, 0, stream>>>(W_Q,  wqb, n4);
    k_f32_to_bf16<<<(n4 + 255) / 256, 256, 0, stream>>>(W_K,  wkb, n4);
    k_f32_to_bf16<<<(n4 + 255) / 256, 256, 0, stream>>>(W_V,  wvb, n4);
    k_f32_to_bf16<<<(n4 + 255) / 256, 256, 0, stream>>>(W_gw, wgb, n4);
    k_f32_to_bf16<<<(n4 + 255) / 256, 256, 0, stream>>>(W_O,  wob, n4);

    k_gemm_qkvg<<<dim3(16, 64), 256, 0, stream>>>(xb, wqb, wkb, wvb, wgb, W_gb, qb, kb, vb, gb);
    k_chunk_sums<<<B_ * H_ * NC_, 256, 0, stream>>>(kb, vb, Ssum, zsum, decay_log);
    k_chunk_scan<<<B_ * H_ * NC_, 128, 0, stream>>>(Ssum, zsum, decay_log);
    k_chunk_out<<<B_ * H_ * NC_, 256, 0, stream>>>(qb, kb, vb, gb, Ssum, zsum, ogb, decay_log);
    k_gemm_out<<<dim3(8, 64), 256, 0, stream>>>(ogb, wob, y);
}

// Round 3
// 232.617 us; speedup vs baseline: 1.0035x; 1.0035x over previous
//
#include <hip/hip_runtime.h>
#include <cstdint>
#include <cstddef>

#define B_   4
#define T_   2048
#define D_   1024
#define H_   8
#define DK_  64
#define HD_  512      // H*DK
#define CH_  64       // chunk length
#define NC_  32       // T_/CH_
#define EPS_ 1e-6f

typedef __attribute__((ext_vector_type(4))) float f32x4;
typedef __attribute__((ext_vector_type(8))) short s16x8;

__device__ __forceinline__ unsigned short f2bf(float f) {
    unsigned int x = __float_as_uint(f);
    unsigned int r = (x + 0x7FFFu + ((x >> 16) & 1u)) >> 16;
    return (unsigned short)r;
}
__device__ __forceinline__ float bf2f(unsigned short u) {
    return __uint_as_float(((unsigned int)u) << 16);
}
__device__ __forceinline__ void ld4(const float* p, float* o) {
    float4 v = *(const float4*)p; o[0]=v.x; o[1]=v.y; o[2]=v.z; o[3]=v.w;
}
// async global->LDS, 16B per lane; LDS dest = wave-uniform base + lane*16
__device__ __forceinline__ void gl_lds16(const unsigned short* g, unsigned short* l) {
    __builtin_amdgcn_global_load_lds(
        (const __attribute__((address_space(1))) unsigned int*)g,
        (__attribute__((address_space(3))) unsigned int*)l, 16, 0, 0);
}

// ---------------- K0: fused fp32 -> bf16 convert for all six tensors ----------------
// x: 8192 blocks (2097152 groups of 4); then 5 weights x 512 blocks (131072 groups each)
__global__ __launch_bounds__(256) void k_cvt_all(
    const float* __restrict__ x,
    const float* __restrict__ wq, const float* __restrict__ wk,
    const float* __restrict__ wv, const float* __restrict__ wgw,
    const float* __restrict__ wo,
    unsigned short* __restrict__ xb,
    unsigned short* __restrict__ wqb, unsigned short* __restrict__ wkb,
    unsigned short* __restrict__ wvb, unsigned short* __restrict__ wgb,
    unsigned short* __restrict__ wob)
{
    int bid = blockIdx.x;
    const float* src; unsigned short* dst; int idx;
    if (bid < 8192) {
        src = x; dst = xb; idx = bid * 256 + threadIdx.x;
    } else {
        int r = bid - 8192;
        int w = r >> 9;
        idx = (r & 511) * 256 + threadIdx.x;
        switch (w) {
            case 0:  src = wq;  dst = wqb; break;
            case 1:  src = wk;  dst = wkb; break;
            case 2:  src = wv;  dst = wvb; break;
            case 3:  src = wgw; dst = wgb; break;
            default: src = wo;  dst = wob; break;
        }
    }
    float4 v = ((const float4*)src)[idx];
    ushort4 o;
    o.x = f2bf(v.x); o.y = f2bf(v.y); o.z = f2bf(v.z); o.w = f2bf(v.w);
    ((ushort4*)dst)[idx] = o;
}

// ---------------- K1: fused QKVG GEMM, bf16 MFMA + async LDS staging ----------------
// grid: (16, 64). blockIdx.x: [0..3]->Q tiles, [4..7]->K, [8..11]->V, [12..15]->G
#define GT_M 128
#define GT_N 128
#define GBK  64
#define LDA  64   // unpadded: required by global_load_lds lane->LDS mapping

__global__ __launch_bounds__(256) void k_gemm_qkvg(
    const unsigned short* __restrict__ xb,
    const unsigned short* __restrict__ wqb, const unsigned short* __restrict__ wkb,
    const unsigned short* __restrict__ wvb, const unsigned short* __restrict__ wgb,
    const float* __restrict__ bias,
    unsigned short* __restrict__ qo, unsigned short* __restrict__ ko,
    unsigned short* __restrict__ vo, unsigned short* __restrict__ go)
{
    __shared__ unsigned short As[GT_M * LDA];
    __shared__ unsigned short Bs[GT_N * LDA];
    const int tid = threadIdx.x;
    const int which = blockIdx.x >> 2;           // 0=Q 1=K 2=V 3=G
    const int nb    = blockIdx.x & 3;
    const int m0    = blockIdx.y * GT_M;
    const int n0    = nb * GT_N;                 // within [0,512)
    const unsigned short* Wp = (which == 0) ? wqb : (which == 1) ? wkb : (which == 2) ? wvb : wgb;
    unsigned short* Op       = (which == 0) ? qo  : (which == 1) ? ko  : (which == 2) ? vo  : go;
    const int K = D_;

    const int lane = tid & 63, wave = tid >> 6;
    const int wm = (wave >> 1) * 64, wn = (wave & 1) * 64;
    const int r16 = lane & 15, quad = lane >> 4;
    const int lrow = lane >> 3, lseg = lane & 7;   // staging: 8 rows x 8 segs per wave-chunk

    f32x4 acc[4][4];
    #pragma unroll
    for (int a = 0; a < 4; a++)
        #pragma unroll
        for (int b = 0; b < 4; b++) acc[a][b] = 0.0f;

    for (int ko_ = 0; ko_ < K; ko_ += GBK) {
        #pragma unroll
        for (int i = 0; i < 4; i++) {
            int chunk = wave * 4 + i;            // 0..15, wave-uniform
            int row = chunk * 8 + lrow;
            gl_lds16(xb + (size_t)(m0 + row) * K + ko_ + lseg * 8, As + chunk * 512);
            gl_lds16(Wp + (size_t)(n0 + row) * K + ko_ + lseg * 8, Bs + chunk * 512);
        }
        __syncthreads();
        #pragma unroll
        for (int kk = 0; kk < GBK; kk += 32) {
            s16x8 af[4], bf[4];
            #pragma unroll
            for (int mt = 0; mt < 4; mt++)
                af[mt] = *(const s16x8*)&As[(wm + mt * 16 + r16) * LDA + kk + quad * 8];
            #pragma unroll
            for (int nt = 0; nt < 4; nt++)
                bf[nt] = *(const s16x8*)&Bs[(wn + nt * 16 + r16) * LDA + kk + quad * 8];
            #pragma unroll
            for (int mt = 0; mt < 4; mt++)
                #pragma unroll
                for (int nt = 0; nt < 4; nt++)
                    acc[mt][nt] = __builtin_amdgcn_mfma_f32_16x16x32_bf16(af[mt], bf[nt], acc[mt][nt], 0, 0, 0);
        }
        __syncthreads();
    }
    #pragma unroll
    for (int mt = 0; mt < 4; mt++) {
        #pragma unroll
        for (int nt = 0; nt < 4; nt++) {
            int col = n0 + wn + nt * 16 + r16;
            float bv = (which == 3) ? bias[col] : 0.0f;
            #pragma unroll
            for (int r = 0; r < 4; r++) {
                int row = m0 + wm + mt * 16 + quad * 4 + r;
                float v = acc[mt][nt][r];
                if (which <= 1)      v = (v > 0.0f) ? v + 1.0f : __builtin_expf(v);     // phi = elu+1
                else if (which == 3) v = 1.0f / (1.0f + __builtin_expf(-(v + bv)));     // sigmoid gate
                Op[(size_t)row * HD_ + col] = f2bf(v);
            }
        }
    }
}

// ---------------- K5: output GEMM: Y = OG @ W_O^T (fp32 out) ----------------
__global__ __launch_bounds__(256) void k_gemm_out(
    const unsigned short* __restrict__ ogb, const unsigned short* __restrict__ wob,
    float* __restrict__ y)
{
    __shared__ unsigned short As[GT_M * LDA];
    __shared__ unsigned short Bs[GT_N * LDA];
    const int tid = threadIdx.x;
    const int m0 = blockIdx.y * GT_M;
    const int n0 = blockIdx.x * GT_N;
    const int K = HD_;   // 512

    const int lane = tid & 63, wave = tid >> 6;
    const int wm = (wave >> 1) * 64, wn = (wave & 1) * 64;
    const int r16 = lane & 15, quad = lane >> 4;
    const int lrow = lane >> 3, lseg = lane & 7;

    f32x4 acc[4][4];
    #pragma unroll
    for (int a = 0; a < 4; a++)
        #pragma unroll
        for (int b = 0; b < 4; b++) acc[a][b] = 0.0f;

    for (int ko_ = 0; ko_ < K; ko_ += GBK) {
        #pragma unroll
        for (int i = 0; i < 4; i++) {
            int chunk = wave * 4 + i;
            int row = chunk * 8 + lrow;
            gl_lds16(ogb + (size_t)(m0 + row) * K + ko_ + lseg * 8, As + chunk * 512);
            gl_lds16(wob + (size_t)(n0 + row) * K + ko_ + lseg * 8, Bs + chunk * 512);
        }
        __syncthreads();
        #pragma unroll
        for (int kk = 0; kk < GBK; kk += 32) {
            s16x8 af[4], bf[4];
            #pragma unroll
            for (int mt = 0; mt < 4; mt++)
                af[mt] = *(const s16x8*)&As[(wm + mt * 16 + r16) * LDA + kk + quad * 8];
            #pragma unroll
            for (int nt = 0; nt < 4; nt++)
                bf[nt] = *(const s16x8*)&Bs[(wn + nt * 16 + r16) * LDA + kk + quad * 8];
            #pragma unroll
            for (int mt = 0; mt < 4; mt++)
                #pragma unroll
                for (int nt = 0; nt < 4; nt++)
                    acc[mt][nt] = __builtin_amdgcn_mfma_f32_16x16x32_bf16(af[mt], bf[nt], acc[mt][nt], 0, 0, 0);
        }
        __syncthreads();
    }
    #pragma unroll
    for (int mt = 0; mt < 4; mt++)
        #pragma unroll
        for (int nt = 0; nt < 4; nt++) {
            int col = n0 + wn + nt * 16 + r16;
            #pragma unroll
            for (int r = 0; r < 4; r++) {
                int row = m0 + wm + mt * 16 + quad * 4 + r;
                y[(size_t)row * D_ + col] = acc[mt][nt][r];
            }
        }
}

// ---------------- K2: per-chunk decayed sums ----------------
__global__ __launch_bounds__(256) void k_chunk_sums(
    const unsigned short* __restrict__ Kb, const unsigned short* __restrict__ Vb,
    float* __restrict__ Ssum, float* __restrict__ zsum, const float* __restrict__ decay_log)
{
    __shared__ float kl[CH_ * 68];
    __shared__ float vl[CH_ * 68];
    const int tid = threadIdx.x;
    const int bc  = blockIdx.x;            // bh*NC_ + c
    const int c   = bc & (NC_ - 1);
    const int bh  = bc >> 5;
    const int h   = bh & (H_ - 1);
    const int b   = bh >> 3;
    const float g  = 1.0f / (1.0f + __builtin_expf(-decay_log[h]));
    const float lg = __builtin_log2f(g);
    const int t0 = c * CH_;

    #pragma unroll
    for (int e = 0; e < 2; e++) {
        int lid = e * 256 + tid;           // 0..511 : 64 rows x 8 segs
        int l = lid >> 3, d0 = (lid & 7) * 8;
        float w = __builtin_exp2f((float)(CH_ - 1 - l) * lg);
        size_t gidx = (size_t)(b * T_ + t0 + l) * HD_ + h * DK_ + d0;
        uint4 kraw = *(const uint4*)(Kb + gidx);
        uint4 vraw = *(const uint4*)(Vb + gidx);
        const unsigned short* kp = (const unsigned short*)&kraw;
        const unsigned short* vp = (const unsigned short*)&vraw;
        #pragma unroll
        for (int j = 0; j < 8; j++) {
            kl[l * 68 + d0 + j] = bf2f(kp[j]) * w;   // decay folded into k
            vl[l * 68 + d0 + j] = bf2f(vp[j]);
        }
    }
    __syncthreads();

    const int ti = tid >> 4, tj = tid & 15;
    const int i0 = ti * 4, j0 = tj * 4;
    float acc[4][4];
    #pragma unroll
    for (int r = 0; r < 4; r++)
        #pragma unroll
        for (int cc = 0; cc < 4; cc++) acc[r][cc] = 0.0f;

    for (int l = 0; l < CH_; l++) {
        float kv[4], vv[4];
        ld4(&kl[l * 68 + i0], kv);
        ld4(&vl[l * 68 + j0], vv);
        #pragma unroll
        for (int r = 0; r < 4; r++)
            #pragma unroll
            for (int cc = 0; cc < 4; cc++) acc[r][cc] += kv[r] * vv[cc];
    }
    size_t base = (size_t)bc * (DK_ * DK_);
    #pragma unroll
    for (int r = 0; r < 4; r++) {
        float4 st = make_float4(acc[r][0], acc[r][1], acc[r][2], acc[r][3]);
        *(float4*)&Ssum[base + (size_t)(i0 + r) * DK_ + j0] = st;
    }
    if (tid < DK_) {
        float s = 0.0f;
        for (int l = 0; l < CH_; l++) s += kl[l * 68 + tid];
        zsum[(size_t)bc * DK_ + tid] = s;
    }
}

// ---------------- K3: exclusive cross-chunk scan (in place) ----------------
__global__ __launch_bounds__(128) void k_chunk_scan(
    float* __restrict__ Ssum, float* __restrict__ zsum, const float* __restrict__ decay_log)
{
    const int tid = threadIdx.x;
    const int grp = blockIdx.x & 31;
    const int bh  = blockIdx.x >> 5;
    const int h   = bh & (H_ - 1);
    const float g  = 1.0f / (1.0f + __builtin_expf(-decay_log[h]));
    const float gC = __builtin_exp2f((float)CH_ * __builtin_log2f(g));   // gamma^CH
    int elem = grp * 128 + tid;                          // 0..4095
    float s = 0.0f;
    for (int c = 0; c < NC_; c++) {
        size_t idx = ((size_t)(bh * NC_ + c)) * 4096 + elem;
        float v = Ssum[idx];
        Ssum[idx] = s;              // exclusive prefix: state BEFORE chunk c
        s = gC * s + v;
    }
    if (grp == 0 && tid < DK_) {
        float z = 0.0f;
        for (int c = 0; c < NC_; c++) {
            size_t idx = ((size_t)(bh * NC_ + c)) * DK_ + tid;
            float v = zsum[idx];
            zsum[idx] = z;
            z = gC * z + v;
        }
    }
}

// ---------------- K4: per-chunk outputs (intra attention + carried state) ----------------
__global__ __launch_bounds__(256) void k_chunk_out(
    const unsigned short* __restrict__ Qb, const unsigned short* __restrict__ Kb,
    const unsigned short* __restrict__ Vb, const unsigned short* __restrict__ Gb,
    const float* __restrict__ Ssum, const float* __restrict__ zsum,
    unsigned short* __restrict__ OGb, const float* __restrict__ decay_log)
{
    __shared__ float BufA[CH_ * 68];   // qT, later scT
    __shared__ float BufB[CH_ * 68];   // kT, later v
    __shared__ float BufC[CH_ * 68];   // S_prev (rows = k-dim, cols = v-dim)
    __shared__ float den_l[CH_];
    __shared__ float zp_l[DK_];
    __shared__ float gpow[CH_ + 1];

    const int tid = threadIdx.x;
    const int bc  = blockIdx.x;
    const int c   = bc & (NC_ - 1);
    const int bh  = bc >> 5;
    const int h   = bh & (H_ - 1);
    const int b   = bh >> 3;
    const float g  = 1.0f / (1.0f + __builtin_expf(-decay_log[h]));
    const float lg = __builtin_log2f(g);
    const int t0 = c * CH_;

    if (tid <= CH_) gpow[tid] = __builtin_exp2f((float)tid * lg);
    if (tid < DK_)  zp_l[tid] = zsum[(size_t)bc * DK_ + tid];

    // load q,k transposed: Buf[d][l]
    #pragma unroll
    for (int e = 0; e < 2; e++) {
        int lid = e * 256 + tid;
        int l = lid >> 3, d0 = (lid & 7) * 8;
        size_t gidx = (size_t)(b * T_ + t0 + l) * HD_ + h * DK_ + d0;
        uint4 qraw = *(const uint4*)(Qb + gidx);
        uint4 kraw = *(const uint4*)(Kb + gidx);
        const unsigned short* qp = (const unsigned short*)&qraw;
        const unsigned short* kp = (const unsigned short*)&kraw;
        #pragma unroll
        for (int j = 0; j < 8; j++) {
            BufA[(d0 + j) * 68 + l] = bf2f(qp[j]);
            BufB[(d0 + j) * 68 + l] = bf2f(kp[j]);
        }
    }
    {   // load S_prev natural layout
        size_t base = (size_t)bc * 4096;
        #pragma unroll
        for (int e = 0; e < 4; e++) {
            int flat = (e * 256 + tid) * 4;
            int row = flat >> 6, c0 = flat & 63;
            *(float4*)&BufC[row * 68 + c0] = *(const float4*)&Ssum[base + flat];
        }
    }
    __syncthreads();

    const int ti = tid >> 4, tj = tid & 15;
    const int i0 = ti * 4, j0 = tj * 4;
    float sc[4][4], it[4][4];
    #pragma unroll
    for (int r = 0; r < 4; r++)
        #pragma unroll
        for (int cc = 0; cc < 4; cc++) { sc[r][cc] = 0.0f; it[r][cc] = 0.0f; }

    for (int d = 0; d < DK_; d++) {
        float qv[4], kv[4], sv[4];
        ld4(&BufA[d * 68 + i0], qv);
        ld4(&BufB[d * 68 + j0], kv);
        ld4(&BufC[d * 68 + j0], sv);
        #pragma unroll
        for (int r = 0; r < 4; r++)
            #pragma unroll
            for (int cc = 0; cc < 4; cc++) {
                sc[r][cc] += qv[r] * kv[cc];
                it[r][cc] += qv[r] * sv[cc];
            }
    }
    // decay weights, causal mask, row sums for denominator
    #pragma unroll
    for (int r = 0; r < 4; r++) {
        int i = i0 + r;
        #pragma unroll
        for (int cc = 0; cc < 4; cc++) {
            int jl = j0 + cc;
            sc[r][cc] = (jl <= i) ? sc[r][cc] * gpow[i - jl] : 0.0f;
            it[r][cc] *= gpow[i + 1];
        }
        float rs = sc[r][0] + sc[r][1] + sc[r][2] + sc[r][3];
        rs += __shfl_xor(rs, 1);
        rs += __shfl_xor(rs, 2);
        rs += __shfl_xor(rs, 4);
        rs += __shfl_xor(rs, 8);
        if (tj == 0) den_l[i] = rs;   // intra part
    }
    __syncthreads();
    if (tid < DK_) {                  // + gamma^(i+1) * q_i . z_prev + eps
        float dp = 0.0f;
        for (int d = 0; d < DK_; d++) dp += BufA[d * 68 + tid] * zp_l[d];
        den_l[tid] += gpow[tid + 1] * dp + EPS_;
    }
    __syncthreads();
    // write scT into BufA; load v into BufB
    #pragma unroll
    for (int cc = 0; cc < 4; cc++) {
        float4 st = make_float4(sc[0][cc], sc[1][cc], sc[2][cc], sc[3][cc]);
        *(float4*)&BufA[(j0 + cc) * 68 + i0] = st;
    }
    #pragma unroll
    for (int e = 0; e < 2; e++) {
        int lid = e * 256 + tid;
        int l = lid >> 3, d0 = (lid & 7) * 8;
        size_t gidx = (size_t)(b * T_ + t0 + l) * HD_ + h * DK_ + d0;
        uint4 vraw = *(const uint4*)(Vb + gidx);
        const unsigned short* vp = (const unsigned short*)&vraw;
        #pragma unroll
        for (int j = 0; j < 8; j++) BufB[l * 68 + d0 + j] = bf2f(vp[j]);
    }
    __syncthreads();

    float og[4][4];
    #pragma unroll
    for (int r = 0; r < 4; r++)
        #pragma unroll
        for (int cc = 0; cc < 4; cc++) og[r][cc] = it[r][cc];

    for (int jl = 0; jl < CH_; jl++) {
        float scv[4], vv[4];
        ld4(&BufA[jl * 68 + i0], scv);
        ld4(&BufB[jl * 68 + j0], vv);
        #pragma unroll
        for (int r = 0; r < 4; r++)
            #pragma unroll
            for (int cc = 0; cc < 4; cc++) og[r][cc] += scv[r] * vv[cc];
    }
    #pragma unroll
    for (int r = 0; r < 4; r++) {
        int i = i0 + r;
        float rcp = 1.0f / den_l[i];
        size_t gidx = (size_t)(b * T_ + t0 + i) * HD_ + h * DK_ + j0;
        ushort4 graw = *(const ushort4*)(Gb + gidx);
        ushort4 o;
        o.x = f2bf(og[r][0] * rcp * bf2f(graw.x));
        o.y = f2bf(og[r][1] * rcp * bf2f(graw.y));
        o.z = f2bf(og[r][2] * rcp * bf2f(graw.z));
        o.w = f2bf(og[r][3] * rcp * bf2f(graw.w));
        *(ushort4*)(OGb + gidx) = o;
    }
}

// ---------------- host ----------------
extern "C" void kernel_launch(void* const* d_in, const int* in_sizes, int n_in,
                              void* d_out, int out_size, void* d_ws, size_t ws_size,
                              hipStream_t stream)
{
    (void)in_sizes; (void)n_in; (void)out_size; (void)ws_size;
    const float* x         = (const float*)d_in[0];
    const float* W_Q       = (const float*)d_in[1];
    const float* W_K       = (const float*)d_in[2];
    const float* W_V       = (const float*)d_in[3];
    const float* W_gw      = (const float*)d_in[4];
    const float* W_gb      = (const float*)d_in[5];
    const float* W_O       = (const float*)d_in[6];
    const float* decay_log = (const float*)d_in[7];
    float* y = (float*)d_out;

    char* ws = (char*)d_ws;
    size_t off = 0;
    auto alloc = [&](size_t bytes) { void* p = ws + off; off += (bytes + 255) & ~(size_t)255; return p; };
    unsigned short* xb   = (unsigned short*)alloc((size_t)B_ * T_ * D_ * 2);
    unsigned short* wqb  = (unsigned short*)alloc((size_t)HD_ * D_ * 2);
    unsigned short* wkb  = (unsigned short*)alloc((size_t)HD_ * D_ * 2);
    unsigned short* wvb  = (unsigned short*)alloc((size_t)HD_ * D_ * 2);
    unsigned short* wgb  = (unsigned short*)alloc((size_t)HD_ * D_ * 2);
    unsigned short* wob  = (unsigned short*)alloc((size_t)D_ * HD_ * 2);
    unsigned short* qb   = (unsigned short*)alloc((size_t)B_ * T_ * HD_ * 2);
    unsigned short* kb   = (unsigned short*)alloc((size_t)B_ * T_ * HD_ * 2);
    unsigned short* vb   = (unsigned short*)alloc((size_t)B_ * T_ * HD_ * 2);
    unsigned short* gb   = (unsigned short*)alloc((size_t)B_ * T_ * HD_ * 2);
    unsigned short* ogb  = (unsigned short*)alloc((size_t)B_ * T_ * HD_ * 2);
    float* Ssum = (float*)alloc((size_t)B_ * H_ * NC_ * DK_ * DK_ * 4);
    float* zsum = (float*)alloc((size_t)B_ * H_ * NC_ * DK_ * 4);

    k_cvt_all<<<8192 + 5 * 512, 256, 0, stream>>>(x, W_Q, W_K, W_V, W_gw, W_O,
                                                  xb, wqb, wkb, wvb, wgb, wob);
    k_gemm_qkvg<<<dim3(16, 64), 256, 0, stream>>>(xb, wqb, wkb, wvb, wgb, W_gb, qb, kb, vb, gb);
    k_chunk_sums<<<B_ * H_ * NC_, 256, 0, stream>>>(kb, vb, Ssum, zsum, decay_log);
    k_chunk_scan<<<B_ * H_ * NC_, 128, 0, stream>>>(Ssum, zsum, decay_log);
    k_chunk_out<<<B_ * H_ * NC_, 256, 0, stream>>>(qb, kb, vb, gb, Ssum, zsum, ogb, decay_log);
    k_gemm_out<<<dim3(8, 64), 256, 0, stream>>>(ogb, wob, y);
}

// Round 4
// 220.558 us; speedup vs baseline: 1.0584x; 1.0547x over previous
//
#include <hip/hip_runtime.h>
#include <cstdint>
#include <cstddef>

#define B_   4
#define T_   2048
#define D_   1024
#define H_   8
#define DK_  64
#define HD_  512      // H*DK
#define CH_  64       // chunk length
#define NC_  32       // T_/CH_
#define EPS_ 1e-6f

typedef __attribute__((ext_vector_type(4))) float f32x4;
typedef __attribute__((ext_vector_type(8))) short s16x8;

__device__ __forceinline__ unsigned short f2bf(float f) {
    unsigned int x = __float_as_uint(f);
    unsigned int r = (x + 0x7FFFu + ((x >> 16) & 1u)) >> 16;
    return (unsigned short)r;
}
__device__ __forceinline__ float bf2f(unsigned short u) {
    return __uint_as_float(((unsigned int)u) << 16);
}
__device__ __forceinline__ void ld4(const float* p, float* o) {
    float4 v = *(const float4*)p; o[0]=v.x; o[1]=v.y; o[2]=v.z; o[3]=v.w;
}
// async global->LDS, 16B per lane; LDS dest = wave-uniform base + lane*16
__device__ __forceinline__ void gl_lds16(const unsigned short* g, unsigned short* l) {
    __builtin_amdgcn_global_load_lds(
        (const __attribute__((address_space(1))) unsigned int*)g,
        (__attribute__((address_space(3))) unsigned int*)l, 16, 0, 0);
}

// ---------------- K0: fused fp32 -> bf16 convert for all six tensors ----------------
__global__ __launch_bounds__(256) void k_cvt_all(
    const float* __restrict__ x,
    const float* __restrict__ wq, const float* __restrict__ wk,
    const float* __restrict__ wv, const float* __restrict__ wgw,
    const float* __restrict__ wo,
    unsigned short* __restrict__ xb,
    unsigned short* __restrict__ wqb, unsigned short* __restrict__ wkb,
    unsigned short* __restrict__ wvb, unsigned short* __restrict__ wgb,
    unsigned short* __restrict__ wob)
{
    int bid = blockIdx.x;
    const float* src; unsigned short* dst; int idx;
    if (bid < 8192) {
        src = x; dst = xb; idx = bid * 256 + threadIdx.x;
    } else {
        int r = bid - 8192;
        int w = r >> 9;
        idx = (r & 511) * 256 + threadIdx.x;
        switch (w) {
            case 0:  src = wq;  dst = wqb; break;
            case 1:  src = wk;  dst = wkb; break;
            case 2:  src = wv;  dst = wvb; break;
            case 3:  src = wgw; dst = wgb; break;
            default: src = wo;  dst = wob; break;
        }
    }
    float4 v = ((const float4*)src)[idx];
    ushort4 o;
    o.x = f2bf(v.x); o.y = f2bf(v.y); o.z = f2bf(v.z); o.w = f2bf(v.w);
    ((ushort4*)dst)[idx] = o;
}

// ---------------- K1: fused QKVG GEMM, bf16 MFMA + async staging + XOR swizzle ----------------
// 1D grid 1024, XCD-swizzled: xcd=id&7 owns m-tiles [xcd*8, xcd*8+8) for all 16 (which,nb) combos.
#define GT_M 128
#define GT_N 128
#define GBK  64
#define LDA  64   // unpadded: required by global_load_lds lane->LDS mapping; XOR swizzle kills conflicts

__global__ __launch_bounds__(256) void k_gemm_qkvg(
    const unsigned short* __restrict__ xb,
    const unsigned short* __restrict__ wqb, const unsigned short* __restrict__ wkb,
    const unsigned short* __restrict__ wvb, const unsigned short* __restrict__ wgb,
    const float* __restrict__ bias,
    unsigned short* __restrict__ qo, unsigned short* __restrict__ ko,
    unsigned short* __restrict__ vo, unsigned short* __restrict__ go)
{
    __shared__ unsigned short As[GT_M * LDA];
    __shared__ unsigned short Bs[GT_N * LDA];
    const int tid = threadIdx.x;
    const int id  = blockIdx.x;
    const int xcd = id & 7, per = id >> 3;
    const int mtile = xcd * 8 + (per & 7);       // 0..63
    const int combo = per >> 3;                  // 0..15
    const int which = combo >> 2;                // 0=Q 1=K 2=V 3=G
    const int nb    = combo & 3;
    const int m0    = mtile * GT_M;
    const int n0    = nb * GT_N;                 // within [0,512)
    const unsigned short* Wp = (which == 0) ? wqb : (which == 1) ? wkb : (which == 2) ? wvb : wgb;
    unsigned short* Op       = (which == 0) ? qo  : (which == 1) ? ko  : (which == 2) ? vo  : go;
    const int K = D_;

    const int lane = tid & 63, wave = tid >> 6;
    const int wm = (wave >> 1) * 64, wn = (wave & 1) * 64;
    const int r16 = lane & 15, quad = lane >> 4;
    const int lrow = lane >> 3, lseg = lane & 7;   // staging: 8 rows x 8 segs per wave-chunk
    const int sseg = lseg ^ lrow;                  // XOR swizzle: LDS granule g of row R holds global seg g^(R&7)
    const int rx   = r16 & 7;                      // read-side swizzle key

    f32x4 acc[4][4];
    #pragma unroll
    for (int a = 0; a < 4; a++)
        #pragma unroll
        for (int b = 0; b < 4; b++) acc[a][b] = 0.0f;

    for (int ko_ = 0; ko_ < K; ko_ += GBK) {
        #pragma unroll
        for (int i = 0; i < 4; i++) {
            int chunk = wave * 4 + i;            // 0..15, wave-uniform
            int row = chunk * 8 + lrow;
            gl_lds16(xb + (size_t)(m0 + row) * K + ko_ + sseg * 8, As + chunk * 512);
            gl_lds16(Wp + (size_t)(n0 + row) * K + ko_ + sseg * 8, Bs + chunk * 512);
        }
        __syncthreads();
        #pragma unroll
        for (int kk = 0; kk < GBK; kk += 32) {
            const int gb_ = kk >> 3;             // granule base: 0 or 4
            s16x8 af[4], bf[4];
            #pragma unroll
            for (int mt = 0; mt < 4; mt++)
                af[mt] = *(const s16x8*)&As[(wm + mt * 16 + r16) * LDA + (((gb_ + quad) ^ rx) << 3)];
            #pragma unroll
            for (int nt = 0; nt < 4; nt++)
                bf[nt] = *(const s16x8*)&Bs[(wn + nt * 16 + r16) * LDA + (((gb_ + quad) ^ rx) << 3)];
            #pragma unroll
            for (int mt = 0; mt < 4; mt++)
                #pragma unroll
                for (int nt = 0; nt < 4; nt++)
                    acc[mt][nt] = __builtin_amdgcn_mfma_f32_16x16x32_bf16(af[mt], bf[nt], acc[mt][nt], 0, 0, 0);
        }
        __syncthreads();
    }
    #pragma unroll
    for (int mt = 0; mt < 4; mt++) {
        #pragma unroll
        for (int nt = 0; nt < 4; nt++) {
            int col = n0 + wn + nt * 16 + r16;
            float bv = (which == 3) ? bias[col] : 0.0f;
            #pragma unroll
            for (int r = 0; r < 4; r++) {
                int row = m0 + wm + mt * 16 + quad * 4 + r;
                float v = acc[mt][nt][r];
                if (which <= 1)      v = (v > 0.0f) ? v + 1.0f : __builtin_expf(v);     // phi = elu+1
                else if (which == 3) v = 1.0f / (1.0f + __builtin_expf(-(v + bv)));     // sigmoid gate
                Op[(size_t)row * HD_ + col] = f2bf(v);
            }
        }
    }
}

// ---------------- K5: output GEMM: Y = OG @ W_O^T (fp32 out) ----------------
// 1D grid 512, XCD-swizzled: xcd owns m-tiles [xcd*8, xcd*8+8) x 8 n-tiles.
__global__ __launch_bounds__(256) void k_gemm_out(
    const unsigned short* __restrict__ ogb, const unsigned short* __restrict__ wob,
    float* __restrict__ y)
{
    __shared__ unsigned short As[GT_M * LDA];
    __shared__ unsigned short Bs[GT_N * LDA];
    const int tid = threadIdx.x;
    const int id  = blockIdx.x;
    const int xcd = id & 7, per = id >> 3;
    const int m0 = (xcd * 8 + (per & 7)) * GT_M;
    const int n0 = (per >> 3) * GT_N;            // 0..7 n-tiles (D_=1024)
    const int K = HD_;   // 512

    const int lane = tid & 63, wave = tid >> 6;
    const int wm = (wave >> 1) * 64, wn = (wave & 1) * 64;
    const int r16 = lane & 15, quad = lane >> 4;
    const int lrow = lane >> 3, lseg = lane & 7;
    const int sseg = lseg ^ lrow;
    const int rx   = r16 & 7;

    f32x4 acc[4][4];
    #pragma unroll
    for (int a = 0; a < 4; a++)
        #pragma unroll
        for (int b = 0; b < 4; b++) acc[a][b] = 0.0f;

    for (int ko_ = 0; ko_ < K; ko_ += GBK) {
        #pragma unroll
        for (int i = 0; i < 4; i++) {
            int chunk = wave * 4 + i;
            int row = chunk * 8 + lrow;
            gl_lds16(ogb + (size_t)(m0 + row) * K + ko_ + sseg * 8, As + chunk * 512);
            gl_lds16(wob + (size_t)(n0 + row) * K + ko_ + sseg * 8, Bs + chunk * 512);
        }
        __syncthreads();
        #pragma unroll
        for (int kk = 0; kk < GBK; kk += 32) {
            const int gb_ = kk >> 3;
            s16x8 af[4], bf[4];
            #pragma unroll
            for (int mt = 0; mt < 4; mt++)
                af[mt] = *(const s16x8*)&As[(wm + mt * 16 + r16) * LDA + (((gb_ + quad) ^ rx) << 3)];
            #pragma unroll
            for (int nt = 0; nt < 4; nt++)
                bf[nt] = *(const s16x8*)&Bs[(wn + nt * 16 + r16) * LDA + (((gb_ + quad) ^ rx) << 3)];
            #pragma unroll
            for (int mt = 0; mt < 4; mt++)
                #pragma unroll
                for (int nt = 0; nt < 4; nt++)
                    acc[mt][nt] = __builtin_amdgcn_mfma_f32_16x16x32_bf16(af[mt], bf[nt], acc[mt][nt], 0, 0, 0);
        }
        __syncthreads();
    }
    #pragma unroll
    for (int mt = 0; mt < 4; mt++)
        #pragma unroll
        for (int nt = 0; nt < 4; nt++) {
            int col = n0 + wn + nt * 16 + r16;
            #pragma unroll
            for (int r = 0; r < 4; r++) {
                int row = m0 + wm + mt * 16 + quad * 4 + r;
                y[(size_t)row * D_ + col] = acc[mt][nt][r];
            }
        }
}

// ---------------- K2: per-chunk decayed sums ----------------
__global__ __launch_bounds__(256) void k_chunk_sums(
    const unsigned short* __restrict__ Kb, const unsigned short* __restrict__ Vb,
    float* __restrict__ Ssum, float* __restrict__ zsum, const float* __restrict__ decay_log)
{
    __shared__ float kl[CH_ * 68];
    __shared__ float vl[CH_ * 68];
    const int tid = threadIdx.x;
    const int bc  = blockIdx.x;            // bh*NC_ + c
    const int c   = bc & (NC_ - 1);
    const int bh  = bc >> 5;
    const int h   = bh & (H_ - 1);
    const int b   = bh >> 3;
    const float g  = 1.0f / (1.0f + __builtin_expf(-decay_log[h]));
    const float lg = __builtin_log2f(g);
    const int t0 = c * CH_;

    #pragma unroll
    for (int e = 0; e < 2; e++) {
        int lid = e * 256 + tid;           // 0..511 : 64 rows x 8 segs
        int l = lid >> 3, d0 = (lid & 7) * 8;
        float w = __builtin_exp2f((float)(CH_ - 1 - l) * lg);
        size_t gidx = (size_t)(b * T_ + t0 + l) * HD_ + h * DK_ + d0;
        uint4 kraw = *(const uint4*)(Kb + gidx);
        uint4 vraw = *(const uint4*)(Vb + gidx);
        const unsigned short* kp = (const unsigned short*)&kraw;
        const unsigned short* vp = (const unsigned short*)&vraw;
        #pragma unroll
        for (int j = 0; j < 8; j++) {
            kl[l * 68 + d0 + j] = bf2f(kp[j]) * w;   // decay folded into k
            vl[l * 68 + d0 + j] = bf2f(vp[j]);
        }
    }
    __syncthreads();

    const int ti = tid >> 4, tj = tid & 15;
    const int i0 = ti * 4, j0 = tj * 4;
    float acc[4][4];
    #pragma unroll
    for (int r = 0; r < 4; r++)
        #pragma unroll
        for (int cc = 0; cc < 4; cc++) acc[r][cc] = 0.0f;

    for (int l = 0; l < CH_; l++) {
        float kv[4], vv[4];
        ld4(&kl[l * 68 + i0], kv);
        ld4(&vl[l * 68 + j0], vv);
        #pragma unroll
        for (int r = 0; r < 4; r++)
            #pragma unroll
            for (int cc = 0; cc < 4; cc++) acc[r][cc] += kv[r] * vv[cc];
    }
    size_t base = (size_t)bc * (DK_ * DK_);
    #pragma unroll
    for (int r = 0; r < 4; r++) {
        float4 st = make_float4(acc[r][0], acc[r][1], acc[r][2], acc[r][3]);
        *(float4*)&Ssum[base + (size_t)(i0 + r) * DK_ + j0] = st;
    }
    if (tid < DK_) {
        float s = 0.0f;
        for (int l = 0; l < CH_; l++) s += kl[l * 68 + tid];
        zsum[(size_t)bc * DK_ + tid] = s;
    }
}

// ---------------- K3: exclusive cross-chunk scan (in place) ----------------
__global__ __launch_bounds__(128) void k_chunk_scan(
    float* __restrict__ Ssum, float* __restrict__ zsum, const float* __restrict__ decay_log)
{
    const int tid = threadIdx.x;
    const int grp = blockIdx.x & 31;
    const int bh  = blockIdx.x >> 5;
    const int h   = bh & (H_ - 1);
    const float g  = 1.0f / (1.0f + __builtin_expf(-decay_log[h]));
    const float gC = __builtin_exp2f((float)CH_ * __builtin_log2f(g));   // gamma^CH
    int elem = grp * 128 + tid;                          // 0..4095
    float s = 0.0f;
    for (int c = 0; c < NC_; c++) {
        size_t idx = ((size_t)(bh * NC_ + c)) * 4096 + elem;
        float v = Ssum[idx];
        Ssum[idx] = s;              // exclusive prefix: state BEFORE chunk c
        s = gC * s + v;
    }
    if (grp == 0 && tid < DK_) {
        float z = 0.0f;
        for (int c = 0; c < NC_; c++) {
            size_t idx = ((size_t)(bh * NC_ + c)) * DK_ + tid;
            float v = zsum[idx];
            zsum[idx] = z;
            z = gC * z + v;
        }
    }
}

// ---------------- K4: per-chunk outputs (intra attention + carried state) ----------------
__global__ __launch_bounds__(256) void k_chunk_out(
    const unsigned short* __restrict__ Qb, const unsigned short* __restrict__ Kb,
    const unsigned short* __restrict__ Vb, const unsigned short* __restrict__ Gb,
    const float* __restrict__ Ssum, const float* __restrict__ zsum,
    unsigned short* __restrict__ OGb, const float* __restrict__ decay_log)
{
    __shared__ float BufA[CH_ * 68];   // qT, later scT
    __shared__ float BufB[CH_ * 68];   // kT, later v
    __shared__ float BufC[CH_ * 68];   // S_prev (rows = k-dim, cols = v-dim)
    __shared__ float den_l[CH_];
    __shared__ float zp_l[DK_];
    __shared__ float gpow[CH_ + 1];

    const int tid = threadIdx.x;
    const int bc  = blockIdx.x;
    const int c   = bc & (NC_ - 1);
    const int bh  = bc >> 5;
    const int h   = bh & (H_ - 1);
    const int b   = bh >> 3;
    const float g  = 1.0f / (1.0f + __builtin_expf(-decay_log[h]));
    const float lg = __builtin_log2f(g);
    const int t0 = c * CH_;

    if (tid <= CH_) gpow[tid] = __builtin_exp2f((float)tid * lg);
    if (tid < DK_)  zp_l[tid] = zsum[(size_t)bc * DK_ + tid];

    // load q,k transposed: Buf[d][l]
    #pragma unroll
    for (int e = 0; e < 2; e++) {
        int lid = e * 256 + tid;
        int l = lid >> 3, d0 = (lid & 7) * 8;
        size_t gidx = (size_t)(b * T_ + t0 + l) * HD_ + h * DK_ + d0;
        uint4 qraw = *(const uint4*)(Qb + gidx);
        uint4 kraw = *(const uint4*)(Kb + gidx);
        const unsigned short* qp = (const unsigned short*)&qraw;
        const unsigned short* kp = (const unsigned short*)&kraw;
        #pragma unroll
        for (int j = 0; j < 8; j++) {
            BufA[(d0 + j) * 68 + l] = bf2f(qp[j]);
            BufB[(d0 + j) * 68 + l] = bf2f(kp[j]);
        }
    }
    {   // load S_prev natural layout
        size_t base = (size_t)bc * 4096;
        #pragma unroll
        for (int e = 0; e < 4; e++) {
            int flat = (e * 256 + tid) * 4;
            int row = flat >> 6, c0 = flat & 63;
            *(float4*)&BufC[row * 68 + c0] = *(const float4*)&Ssum[base + flat];
        }
    }
    __syncthreads();

    const int ti = tid >> 4, tj = tid & 15;
    const int i0 = ti * 4, j0 = tj * 4;
    float sc[4][4], it[4][4];
    #pragma unroll
    for (int r = 0; r < 4; r++)
        #pragma unroll
        for (int cc = 0; cc < 4; cc++) { sc[r][cc] = 0.0f; it[r][cc] = 0.0f; }

    for (int d = 0; d < DK_; d++) {
        float qv[4], kv[4], sv[4];
        ld4(&BufA[d * 68 + i0], qv);
        ld4(&BufB[d * 68 + j0], kv);
        ld4(&BufC[d * 68 + j0], sv);
        #pragma unroll
        for (int r = 0; r < 4; r++)
            #pragma unroll
            for (int cc = 0; cc < 4; cc++) {
                sc[r][cc] += qv[r] * kv[cc];
                it[r][cc] += qv[r] * sv[cc];
            }
    }
    // decay weights, causal mask, row sums for denominator
    #pragma unroll
    for (int r = 0; r < 4; r++) {
        int i = i0 + r;
        #pragma unroll
        for (int cc = 0; cc < 4; cc++) {
            int jl = j0 + cc;
            sc[r][cc] = (jl <= i) ? sc[r][cc] * gpow[i - jl] : 0.0f;
            it[r][cc] *= gpow[i + 1];
        }
        float rs = sc[r][0] + sc[r][1] + sc[r][2] + sc[r][3];
        rs += __shfl_xor(rs, 1);
        rs += __shfl_xor(rs, 2);
        rs += __shfl_xor(rs, 4);
        rs += __shfl_xor(rs, 8);
        if (tj == 0) den_l[i] = rs;   // intra part
    }
    __syncthreads();
    if (tid < DK_) {                  // + gamma^(i+1) * q_i . z_prev + eps
        float dp = 0.0f;
        for (int d = 0; d < DK_; d++) dp += BufA[d * 68 + tid] * zp_l[d];
        den_l[tid] += gpow[tid + 1] * dp + EPS_;
    }
    __syncthreads();
    // write scT into BufA; load v into BufB
    #pragma unroll
    for (int cc = 0; cc < 4; cc++) {
        float4 st = make_float4(sc[0][cc], sc[1][cc], sc[2][cc], sc[3][cc]);
        *(float4*)&BufA[(j0 + cc) * 68 + i0] = st;
    }
    #pragma unroll
    for (int e = 0; e < 2; e++) {
        int lid = e * 256 + tid;
        int l = lid >> 3, d0 = (lid & 7) * 8;
        size_t gidx = (size_t)(b * T_ + t0 + l) * HD_ + h * DK_ + d0;
        uint4 vraw = *(const uint4*)(Vb + gidx);
        const unsigned short* vp = (const unsigned short*)&vraw;
        #pragma unroll
        for (int j = 0; j < 8; j++) BufB[l * 68 + d0 + j] = bf2f(vp[j]);
    }
    __syncthreads();

    float og[4][4];
    #pragma unroll
    for (int r = 0; r < 4; r++)
        #pragma unroll
        for (int cc = 0; cc < 4; cc++) og[r][cc] = it[r][cc];

    for (int jl = 0; jl < CH_; jl++) {
        float scv[4], vv[4];
        ld4(&BufA[jl * 68 + i0], scv);
        ld4(&BufB[jl * 68 + j0], vv);
        #pragma unroll
        for (int r = 0; r < 4; r++)
            #pragma unroll
            for (int cc = 0; cc < 4; cc++) og[r][cc] += scv[r] * vv[cc];
    }
    #pragma unroll
    for (int r = 0; r < 4; r++) {
        int i = i0 + r;
        float rcp = 1.0f / den_l[i];
        size_t gidx = (size_t)(b * T_ + t0 + i) * HD_ + h * DK_ + j0;
        ushort4 graw = *(const ushort4*)(Gb + gidx);
        ushort4 o;
        o.x = f2bf(og[r][0] * rcp * bf2f(graw.x));
        o.y = f2bf(og[r][1] * rcp * bf2f(graw.y));
        o.z = f2bf(og[r][2] * rcp * bf2f(graw.z));
        o.w = f2bf(og[r][3] * rcp * bf2f(graw.w));
        *(ushort4*)(OGb + gidx) = o;
    }
}

// ---------------- host ----------------
extern "C" void kernel_launch(void* const* d_in, const int* in_sizes, int n_in,
                              void* d_out, int out_size, void* d_ws, size_t ws_size,
                              hipStream_t stream)
{
    (void)in_sizes; (void)n_in; (void)out_size; (void)ws_size;
    const float* x         = (const float*)d_in[0];
    const float* W_Q       = (const float*)d_in[1];
    const float* W_K       = (const float*)d_in[2];
    const float* W_V       = (const float*)d_in[3];
    const float* W_gw      = (const float*)d_in[4];
    const float* W_gb      = (const float*)d_in[5];
    const float* W_O       = (const float*)d_in[6];
    const float* decay_log = (const float*)d_in[7];
    float* y = (float*)d_out;

    char* ws = (char*)d_ws;
    size_t off = 0;
    auto alloc = [&](size_t bytes) { void* p = ws + off; off += (bytes + 255) & ~(size_t)255; return p; };
    unsigned short* xb   = (unsigned short*)alloc((size_t)B_ * T_ * D_ * 2);
    unsigned short* wqb  = (unsigned short*)alloc((size_t)HD_ * D_ * 2);
    unsigned short* wkb  = (unsigned short*)alloc((size_t)HD_ * D_ * 2);
    unsigned short* wvb  = (unsigned short*)alloc((size_t)HD_ * D_ * 2);
    unsigned short* wgb  = (unsigned short*)alloc((size_t)HD_ * D_ * 2);
    unsigned short* wob  = (unsigned short*)alloc((size_t)D_ * HD_ * 2);
    unsigned short* qb   = (unsigned short*)alloc((size_t)B_ * T_ * HD_ * 2);
    unsigned short* kb   = (unsigned short*)alloc((size_t)B_ * T_ * HD_ * 2);
    unsigned short* vb   = (unsigned short*)alloc((size_t)B_ * T_ * HD_ * 2);
    unsigned short* gb   = (unsigned short*)alloc((size_t)B_ * T_ * HD_ * 2);
    unsigned short* ogb  = (unsigned short*)alloc((size_t)B_ * T_ * HD_ * 2);
    float* Ssum = (float*)alloc((size_t)B_ * H_ * NC_ * DK_ * DK_ * 4);
    float* zsum = (float*)alloc((size_t)B_ * H_ * NC_ * DK_ * 4);

    k_cvt_all<<<8192 + 5 * 512, 256, 0, stream>>>(x, W_Q, W_K, W_V, W_gw, W_O,
                                                  xb, wqb, wkb, wvb, wgb, wob);
    k_gemm_qkvg<<<1024, 256, 0, stream>>>(xb, wqb, wkb, wvb, wgb, W_gb, qb, kb, vb, gb);
    k_chunk_sums<<<B_ * H_ * NC_, 256, 0, stream>>>(kb, vb, Ssum, zsum, decay_log);
    k_chunk_scan<<<B_ * H_ * NC_, 128, 0, stream>>>(Ssum, zsum, decay_log);
    k_chunk_out<<<B_ * H_ * NC_, 256, 0, stream>>>(qb, kb, vb, gb, Ssum, zsum, ogb, decay_log);
    k_gemm_out<<<512, 256, 0, stream>>>(ogb, wob, y);
}

// Round 5
// 217.622 us; speedup vs baseline: 1.0726x; 1.0135x over previous
//
#include <hip/hip_runtime.h>
#include <cstdint>
#include <cstddef>

#define B_   4
#define T_   2048
#define D_   1024
#define H_   8
#define DK_  64
#define HD_  512      // H*DK
#define CH_  64       // chunk length
#define NC_  32       // T_/CH_
#define EPS_ 1e-6f

typedef __attribute__((ext_vector_type(4))) float f32x4;
typedef __attribute__((ext_vector_type(8))) short s16x8;

__device__ __forceinline__ unsigned short f2bf(float f) {
    unsigned int x = __float_as_uint(f);
    unsigned int r = (x + 0x7FFFu + ((x >> 16) & 1u)) >> 16;
    return (unsigned short)r;
}
__device__ __forceinline__ float bf2f(unsigned short u) {
    return __uint_as_float(((unsigned int)u) << 16);
}
__device__ __forceinline__ void ld4(const float* p, float* o) {
    float4 v = *(const float4*)p; o[0]=v.x; o[1]=v.y; o[2]=v.z; o[3]=v.w;
}
// async global->LDS, 16B per lane; LDS dest = wave-uniform base + lane*16
__device__ __forceinline__ void gl_lds16(const unsigned short* g, unsigned short* l) {
    __builtin_amdgcn_global_load_lds(
        (const __attribute__((address_space(1))) unsigned int*)g,
        (__attribute__((address_space(3))) unsigned int*)l, 16, 0, 0);
}

// ---------------- K0: fused fp32 -> bf16 convert for all six tensors ----------------
__global__ __launch_bounds__(256) void k_cvt_all(
    const float* __restrict__ x,
    const float* __restrict__ wq, const float* __restrict__ wk,
    const float* __restrict__ wv, const float* __restrict__ wgw,
    const float* __restrict__ wo,
    unsigned short* __restrict__ xb,
    unsigned short* __restrict__ wqb, unsigned short* __restrict__ wkb,
    unsigned short* __restrict__ wvb, unsigned short* __restrict__ wgb,
    unsigned short* __restrict__ wob)
{
    int bid = blockIdx.x;
    const float* src; unsigned short* dst; int idx;
    if (bid < 8192) {
        src = x; dst = xb; idx = bid * 256 + threadIdx.x;
    } else {
        int r = bid - 8192;
        int w = r >> 9;
        idx = (r & 511) * 256 + threadIdx.x;
        switch (w) {
            case 0:  src = wq;  dst = wqb; break;
            case 1:  src = wk;  dst = wkb; break;
            case 2:  src = wv;  dst = wvb; break;
            case 3:  src = wgw; dst = wgb; break;
            default: src = wo;  dst = wob; break;
        }
    }
    float4 v = ((const float4*)src)[idx];
    ushort4 o;
    o.x = f2bf(v.x); o.y = f2bf(v.y); o.z = f2bf(v.z); o.w = f2bf(v.w);
    ((ushort4*)dst)[idx] = o;
}

// ---------------- K1: fused QKVG GEMM, double-buffered async staging + XOR swizzle ----------------
#define GT_M 128
#define GT_N 128
#define GBK  64
#define LDA  64   // unpadded: required by global_load_lds; XOR swizzle kills conflicts

__global__ __launch_bounds__(256) void k_gemm_qkvg(
    const unsigned short* __restrict__ xb,
    const unsigned short* __restrict__ wqb, const unsigned short* __restrict__ wkb,
    const unsigned short* __restrict__ wvb, const unsigned short* __restrict__ wgb,
    const float* __restrict__ bias,
    unsigned short* __restrict__ qo, unsigned short* __restrict__ ko,
    unsigned short* __restrict__ vo, unsigned short* __restrict__ go)
{
    __shared__ unsigned short As[2][GT_M * LDA];
    __shared__ unsigned short Bs[2][GT_N * LDA];
    const int tid = threadIdx.x;
    const int id  = blockIdx.x;
    const int xcd = id & 7, per = id >> 3;
    const int mtile = xcd * 8 + (per & 7);       // 0..63
    const int combo = per >> 3;                  // 0..15
    const int which = combo >> 2;                // 0=Q 1=K 2=V 3=G
    const int nb    = combo & 3;
    const int m0    = mtile * GT_M;
    const int n0    = nb * GT_N;                 // within [0,512)
    const unsigned short* Wp = (which == 0) ? wqb : (which == 1) ? wkb : (which == 2) ? wvb : wgb;
    unsigned short* Op       = (which == 0) ? qo  : (which == 1) ? ko  : (which == 2) ? vo  : go;
    const int K = D_;
    const int NIT = K / GBK;                     // 16

    const int lane = tid & 63, wave = tid >> 6;
    const int wm = (wave >> 1) * 64, wn = (wave & 1) * 64;
    const int r16 = lane & 15, quad = lane >> 4;
    const int lrow = lane >> 3, lseg = lane & 7;   // staging: 8 rows x 8 segs per wave-chunk
    const int sseg = lseg ^ lrow;                  // XOR swizzle
    const int rx   = r16 & 7;                      // read-side swizzle key

    f32x4 acc[4][4];
    #pragma unroll
    for (int a = 0; a < 4; a++)
        #pragma unroll
        for (int b = 0; b < 4; b++) acc[a][b] = 0.0f;

    const int srow = wave * 32 + lrow * 4;       // not used; keep simple below

    // stage buf, K-offset ko_
    auto stage = [&](int buf, int ko_) {
        #pragma unroll
        for (int i = 0; i < 4; i++) {
            int chunk = wave * 4 + i;            // 0..15, wave-uniform
            int row = chunk * 8 + lrow;
            gl_lds16(xb + (size_t)(m0 + row) * K + ko_ + sseg * 8, &As[buf][chunk * 512]);
            gl_lds16(Wp + (size_t)(n0 + row) * K + ko_ + sseg * 8, &Bs[buf][chunk * 512]);
        }
    };

    stage(0, 0);
    for (int it = 0; it < NIT; ++it) {
        __syncthreads();                          // drains own loads for buf it&1
        if (it + 1 < NIT) stage((it + 1) & 1, (it + 1) * GBK);   // in flight during MFMA
        const int buf = it & 1;
        #pragma unroll
        for (int kk = 0; kk < GBK; kk += 32) {
            const int gb_ = kk >> 3;             // granule base: 0 or 4
            s16x8 af[4], bf[4];
            #pragma unroll
            for (int mt = 0; mt < 4; mt++)
                af[mt] = *(const s16x8*)&As[buf][(wm + mt * 16 + r16) * LDA + (((gb_ + quad) ^ rx) << 3)];
            #pragma unroll
            for (int nt = 0; nt < 4; nt++)
                bf[nt] = *(const s16x8*)&Bs[buf][(wn + nt * 16 + r16) * LDA + (((gb_ + quad) ^ rx) << 3)];
            #pragma unroll
            for (int mt = 0; mt < 4; mt++)
                #pragma unroll
                for (int nt = 0; nt < 4; nt++)
                    acc[mt][nt] = __builtin_amdgcn_mfma_f32_16x16x32_bf16(af[mt], bf[nt], acc[mt][nt], 0, 0, 0);
        }
        __syncthreads();
    }
    (void)srow;
    #pragma unroll
    for (int mt = 0; mt < 4; mt++) {
        #pragma unroll
        for (int nt = 0; nt < 4; nt++) {
            int col = n0 + wn + nt * 16 + r16;
            float bv = (which == 3) ? bias[col] : 0.0f;
            #pragma unroll
            for (int r = 0; r < 4; r++) {
                int row = m0 + wm + mt * 16 + quad * 4 + r;
                float v = acc[mt][nt][r];
                if (which <= 1)      v = (v > 0.0f) ? v + 1.0f : __builtin_expf(v);     // phi = elu+1
                else if (which == 3) v = 1.0f / (1.0f + __builtin_expf(-(v + bv)));     // sigmoid gate
                Op[(size_t)row * HD_ + col] = f2bf(v);
            }
        }
    }
}

// ---------------- K5: output GEMM: Y = OG @ W_O^T (fp32 out), double-buffered ----------------
__global__ __launch_bounds__(256) void k_gemm_out(
    const unsigned short* __restrict__ ogb, const unsigned short* __restrict__ wob,
    float* __restrict__ y)
{
    __shared__ unsigned short As[2][GT_M * LDA];
    __shared__ unsigned short Bs[2][GT_N * LDA];
    const int tid = threadIdx.x;
    const int id  = blockIdx.x;
    const int xcd = id & 7, per = id >> 3;
    const int m0 = (xcd * 8 + (per & 7)) * GT_M;
    const int n0 = (per >> 3) * GT_N;            // 0..7 n-tiles (D_=1024)
    const int K = HD_;   // 512
    const int NIT = K / GBK;                     // 8

    const int lane = tid & 63, wave = tid >> 6;
    const int wm = (wave >> 1) * 64, wn = (wave & 1) * 64;
    const int r16 = lane & 15, quad = lane >> 4;
    const int lrow = lane >> 3, lseg = lane & 7;
    const int sseg = lseg ^ lrow;
    const int rx   = r16 & 7;

    f32x4 acc[4][4];
    #pragma unroll
    for (int a = 0; a < 4; a++)
        #pragma unroll
        for (int b = 0; b < 4; b++) acc[a][b] = 0.0f;

    auto stage = [&](int buf, int ko_) {
        #pragma unroll
        for (int i = 0; i < 4; i++) {
            int chunk = wave * 4 + i;
            int row = chunk * 8 + lrow;
            gl_lds16(ogb + (size_t)(m0 + row) * K + ko_ + sseg * 8, &As[buf][chunk * 512]);
            gl_lds16(wob + (size_t)(n0 + row) * K + ko_ + sseg * 8, &Bs[buf][chunk * 512]);
        }
    };

    stage(0, 0);
    for (int it = 0; it < NIT; ++it) {
        __syncthreads();
        if (it + 1 < NIT) stage((it + 1) & 1, (it + 1) * GBK);
        const int buf = it & 1;
        #pragma unroll
        for (int kk = 0; kk < GBK; kk += 32) {
            const int gb_ = kk >> 3;
            s16x8 af[4], bf[4];
            #pragma unroll
            for (int mt = 0; mt < 4; mt++)
                af[mt] = *(const s16x8*)&As[buf][(wm + mt * 16 + r16) * LDA + (((gb_ + quad) ^ rx) << 3)];
            #pragma unroll
            for (int nt = 0; nt < 4; nt++)
                bf[nt] = *(const s16x8*)&Bs[buf][(wn + nt * 16 + r16) * LDA + (((gb_ + quad) ^ rx) << 3)];
            #pragma unroll
            for (int mt = 0; mt < 4; mt++)
                #pragma unroll
                for (int nt = 0; nt < 4; nt++)
                    acc[mt][nt] = __builtin_amdgcn_mfma_f32_16x16x32_bf16(af[mt], bf[nt], acc[mt][nt], 0, 0, 0);
        }
        __syncthreads();
    }
    #pragma unroll
    for (int mt = 0; mt < 4; mt++)
        #pragma unroll
        for (int nt = 0; nt < 4; nt++) {
            int col = n0 + wn + nt * 16 + r16;
            #pragma unroll
            for (int r = 0; r < 4; r++) {
                int row = m0 + wm + mt * 16 + quad * 4 + r;
                y[(size_t)row * D_ + col] = acc[mt][nt][r];
            }
        }
}

// ---------------- K2: per-chunk decayed sums ----------------
__global__ __launch_bounds__(256) void k_chunk_sums(
    const unsigned short* __restrict__ Kb, const unsigned short* __restrict__ Vb,
    float* __restrict__ Ssum, float* __restrict__ zsum, const float* __restrict__ decay_log)
{
    __shared__ float kl[CH_ * 68];
    __shared__ float vl[CH_ * 68];
    const int tid = threadIdx.x;
    const int bc  = blockIdx.x;            // bh*NC_ + c
    const int c   = bc & (NC_ - 1);
    const int bh  = bc >> 5;
    const int h   = bh & (H_ - 1);
    const int b   = bh >> 3;
    const float g  = 1.0f / (1.0f + __builtin_expf(-decay_log[h]));
    const float lg = __builtin_log2f(g);
    const int t0 = c * CH_;

    #pragma unroll
    for (int e = 0; e < 2; e++) {
        int lid = e * 256 + tid;           // 0..511 : 64 rows x 8 segs
        int l = lid >> 3, d0 = (lid & 7) * 8;
        float w = __builtin_exp2f((float)(CH_ - 1 - l) * lg);
        size_t gidx = (size_t)(b * T_ + t0 + l) * HD_ + h * DK_ + d0;
        uint4 kraw = *(const uint4*)(Kb + gidx);
        uint4 vraw = *(const uint4*)(Vb + gidx);
        const unsigned short* kp = (const unsigned short*)&kraw;
        const unsigned short* vp = (const unsigned short*)&vraw;
        #pragma unroll
        for (int j = 0; j < 8; j++) {
            kl[l * 68 + d0 + j] = bf2f(kp[j]) * w;   // decay folded into k
            vl[l * 68 + d0 + j] = bf2f(vp[j]);
        }
    }
    __syncthreads();

    const int ti = tid >> 4, tj = tid & 15;
    const int i0 = ti * 4, j0 = tj * 4;
    float acc[4][4];
    #pragma unroll
    for (int r = 0; r < 4; r++)
        #pragma unroll
        for (int cc = 0; cc < 4; cc++) acc[r][cc] = 0.0f;

    for (int l = 0; l < CH_; l++) {
        float kv[4], vv[4];
        ld4(&kl[l * 68 + i0], kv);
        ld4(&vl[l * 68 + j0], vv);
        #pragma unroll
        for (int r = 0; r < 4; r++)
            #pragma unroll
            for (int cc = 0; cc < 4; cc++) acc[r][cc] += kv[r] * vv[cc];
    }
    size_t base = (size_t)bc * (DK_ * DK_);
    #pragma unroll
    for (int r = 0; r < 4; r++) {
        float4 st = make_float4(acc[r][0], acc[r][1], acc[r][2], acc[r][3]);
        *(float4*)&Ssum[base + (size_t)(i0 + r) * DK_ + j0] = st;
    }
    if (tid < DK_) {
        float s = 0.0f;
        for (int l = 0; l < CH_; l++) s += kl[l * 68 + tid];
        zsum[(size_t)bc * DK_ + tid] = s;
    }
}

// ---------------- K3: exclusive cross-chunk scan (in place) ----------------
__global__ __launch_bounds__(128) void k_chunk_scan(
    float* __restrict__ Ssum, float* __restrict__ zsum, const float* __restrict__ decay_log)
{
    const int tid = threadIdx.x;
    const int grp = blockIdx.x & 31;
    const int bh  = blockIdx.x >> 5;
    const int h   = bh & (H_ - 1);
    const float g  = 1.0f / (1.0f + __builtin_expf(-decay_log[h]));
    const float gC = __builtin_exp2f((float)CH_ * __builtin_log2f(g));   // gamma^CH
    int elem = grp * 128 + tid;                          // 0..4095
    float s = 0.0f;
    for (int c = 0; c < NC_; c++) {
        size_t idx = ((size_t)(bh * NC_ + c)) * 4096 + elem;
        float v = Ssum[idx];
        Ssum[idx] = s;              // exclusive prefix: state BEFORE chunk c
        s = gC * s + v;
    }
    if (grp == 0 && tid < DK_) {
        float z = 0.0f;
        for (int c = 0; c < NC_; c++) {
            size_t idx = ((size_t)(bh * NC_ + c)) * DK_ + tid;
            float v = zsum[idx];
            zsum[idx] = z;
            z = gC * z + v;
        }
    }
}

// ---------------- K4: per-chunk outputs (intra attention + carried state) ----------------
__global__ __launch_bounds__(256) void k_chunk_out(
    const unsigned short* __restrict__ Qb, const unsigned short* __restrict__ Kb,
    const unsigned short* __restrict__ Vb, const unsigned short* __restrict__ Gb,
    const float* __restrict__ Ssum, const float* __restrict__ zsum,
    unsigned short* __restrict__ OGb, const float* __restrict__ decay_log)
{
    __shared__ float BufA[CH_ * 68];   // qT, later scT
    __shared__ float BufB[CH_ * 68];   // kT, later v
    __shared__ float BufC[CH_ * 68];   // S_prev (rows = k-dim, cols = v-dim)
    __shared__ float den_l[CH_];
    __shared__ float zp_l[DK_];
    __shared__ float gpow[CH_ + 1];

    const int tid = threadIdx.x;
    const int bc  = blockIdx.x;
    const int c   = bc & (NC_ - 1);
    const int bh  = bc >> 5;
    const int h   = bh & (H_ - 1);
    const int b   = bh >> 3;
    const float g  = 1.0f / (1.0f + __builtin_expf(-decay_log[h]));
    const float lg = __builtin_log2f(g);
    const int t0 = c * CH_;

    if (tid <= CH_) gpow[tid] = __builtin_exp2f((float)tid * lg);
    if (tid < DK_)  zp_l[tid] = zsum[(size_t)bc * DK_ + tid];

    // load q,k transposed: Buf[d][l]
    #pragma unroll
    for (int e = 0; e < 2; e++) {
        int lid = e * 256 + tid;
        int l = lid >> 3, d0 = (lid & 7) * 8;
        size_t gidx = (size_t)(b * T_ + t0 + l) * HD_ + h * DK_ + d0;
        uint4 qraw = *(const uint4*)(Qb + gidx);
        uint4 kraw = *(const uint4*)(Kb + gidx);
        const unsigned short* qp = (const unsigned short*)&qraw;
        const unsigned short* kp = (const unsigned short*)&kraw;
        #pragma unroll
        for (int j = 0; j < 8; j++) {
            BufA[(d0 + j) * 68 + l] = bf2f(qp[j]);
            BufB[(d0 + j) * 68 + l] = bf2f(kp[j]);
        }
    }
    {   // load S_prev natural layout
        size_t base = (size_t)bc * 4096;
        #pragma unroll
        for (int e = 0; e < 4; e++) {
            int flat = (e * 256 + tid) * 4;
            int row = flat >> 6, c0 = flat & 63;
            *(float4*)&BufC[row * 68 + c0] = *(const float4*)&Ssum[base + flat];
        }
    }
    __syncthreads();

    const int ti = tid >> 4, tj = tid & 15;
    const int i0 = ti * 4, j0 = tj * 4;
    float sc[4][4], it[4][4];
    #pragma unroll
    for (int r = 0; r < 4; r++)
        #pragma unroll
        for (int cc = 0; cc < 4; cc++) { sc[r][cc] = 0.0f; it[r][cc] = 0.0f; }

    for (int d = 0; d < DK_; d++) {
        float qv[4], kv[4], sv[4];
        ld4(&BufA[d * 68 + i0], qv);
        ld4(&BufB[d * 68 + j0], kv);
        ld4(&BufC[d * 68 + j0], sv);
        #pragma unroll
        for (int r = 0; r < 4; r++)
            #pragma unroll
            for (int cc = 0; cc < 4; cc++) {
                sc[r][cc] += qv[r] * kv[cc];
                it[r][cc] += qv[r] * sv[cc];
            }
    }
    // decay weights, causal mask, row sums for denominator
    #pragma unroll
    for (int r = 0; r < 4; r++) {
        int i = i0 + r;
        #pragma unroll
        for (int cc = 0; cc < 4; cc++) {
            int jl = j0 + cc;
            sc[r][cc] = (jl <= i) ? sc[r][cc] * gpow[i - jl] : 0.0f;
            it[r][cc] *= gpow[i + 1];
        }
        float rs = sc[r][0] + sc[r][1] + sc[r][2] + sc[r][3];
        rs += __shfl_xor(rs, 1);
        rs += __shfl_xor(rs, 2);
        rs += __shfl_xor(rs, 4);
        rs += __shfl_xor(rs, 8);
        if (tj == 0) den_l[i] = rs;   // intra part
    }
    __syncthreads();
    if (tid < DK_) {                  // + gamma^(i+1) * q_i . z_prev + eps
        float dp = 0.0f;
        for (int d = 0; d < DK_; d++) dp += BufA[d * 68 + tid] * zp_l[d];
        den_l[tid] += gpow[tid + 1] * dp + EPS_;
    }
    __syncthreads();
    // write scT into BufA; load v into BufB
    #pragma unroll
    for (int cc = 0; cc < 4; cc++) {
        float4 st = make_float4(sc[0][cc], sc[1][cc], sc[2][cc], sc[3][cc]);
        *(float4*)&BufA[(j0 + cc) * 68 + i0] = st;
    }
    #pragma unroll
    for (int e = 0; e < 2; e++) {
        int lid = e * 256 + tid;
        int l = lid >> 3, d0 = (lid & 7) * 8;
        size_t gidx = (size_t)(b * T_ + t0 + l) * HD_ + h * DK_ + d0;
        uint4 vraw = *(const uint4*)(Vb + gidx);
        const unsigned short* vp = (const unsigned short*)&vraw;
        #pragma unroll
        for (int j = 0; j < 8; j++) BufB[l * 68 + d0 + j] = bf2f(vp[j]);
    }
    __syncthreads();

    float og[4][4];
    #pragma unroll
    for (int r = 0; r < 4; r++)
        #pragma unroll
        for (int cc = 0; cc < 4; cc++) og[r][cc] = it[r][cc];

    for (int jl = 0; jl < CH_; jl++) {
        float scv[4], vv[4];
        ld4(&BufA[jl * 68 + i0], scv);
        ld4(&BufB[jl * 68 + j0], vv);
        #pragma unroll
        for (int r = 0; r < 4; r++)
            #pragma unroll
            for (int cc = 0; cc < 4; cc++) og[r][cc] += scv[r] * vv[cc];
    }
    #pragma unroll
    for (int r = 0; r < 4; r++) {
        int i = i0 + r;
        float rcp = 1.0f / den_l[i];
        size_t gidx = (size_t)(b * T_ + t0 + i) * HD_ + h * DK_ + j0;
        ushort4 graw = *(const ushort4*)(Gb + gidx);
        ushort4 o;
        o.x = f2bf(og[r][0] * rcp * bf2f(graw.x));
        o.y = f2bf(og[r][1] * rcp * bf2f(graw.y));
        o.z = f2bf(og[r][2] * rcp * bf2f(graw.z));
        o.w = f2bf(og[r][3] * rcp * bf2f(graw.w));
        *(ushort4*)(OGb + gidx) = o;
    }
}

// ---------------- host ----------------
extern "C" void kernel_launch(void* const* d_in, const int* in_sizes, int n_in,
                              void* d_out, int out_size, void* d_ws, size_t ws_size,
                              hipStream_t stream)
{
    (void)in_sizes; (void)n_in; (void)out_size; (void)ws_size;
    const float* x         = (const float*)d_in[0];
    const float* W_Q       = (const float*)d_in[1];
    const float* W_K       = (const float*)d_in[2];
    const float* W_V       = (const float*)d_in[3];
    const float* W_gw      = (const float*)d_in[4];
    const float* W_gb      = (const float*)d_in[5];
    const float* W_O       = (const float*)d_in[6];
    const float* decay_log = (const float*)d_in[7];
    float* y = (float*)d_out;

    char* ws = (char*)d_ws;
    size_t off = 0;
    auto alloc = [&](size_t bytes) { void* p = ws + off; off += (bytes + 255) & ~(size_t)255; return p; };
    unsigned short* xb   = (unsigned short*)alloc((size_t)B_ * T_ * D_ * 2);
    unsigned short* wqb  = (unsigned short*)alloc((size_t)HD_ * D_ * 2);
    unsigned short* wkb  = (unsigned short*)alloc((size_t)HD_ * D_ * 2);
    unsigned short* wvb  = (unsigned short*)alloc((size_t)HD_ * D_ * 2);
    unsigned short* wgb  = (unsigned short*)alloc((size_t)HD_ * D_ * 2);
    unsigned short* wob  = (unsigned short*)alloc((size_t)D_ * HD_ * 2);
    unsigned short* qb   = (unsigned short*)alloc((size_t)B_ * T_ * HD_ * 2);
    unsigned short* kb   = (unsigned short*)alloc((size_t)B_ * T_ * HD_ * 2);
    unsigned short* vb   = (unsigned short*)alloc((size_t)B_ * T_ * HD_ * 2);
    unsigned short* gb   = (unsigned short*)alloc((size_t)B_ * T_ * HD_ * 2);
    unsigned short* ogb  = (unsigned short*)alloc((size_t)B_ * T_ * HD_ * 2);
    float* Ssum = (float*)alloc((size_t)B_ * H_ * NC_ * DK_ * DK_ * 4);
    float* zsum = (float*)alloc((size_t)B_ * H_ * NC_ * DK_ * 4);

    k_cvt_all<<<8192 + 5 * 512, 256, 0, stream>>>(x, W_Q, W_K, W_V, W_gw, W_O,
                                                  xb, wqb, wkb, wvb, wgb, wob);
    k_gemm_qkvg<<<1024, 256, 0, stream>>>(xb, wqb, wkb, wvb, wgb, W_gb, qb, kb, vb, gb);
    k_chunk_sums<<<B_ * H_ * NC_, 256, 0, stream>>>(kb, vb, Ssum, zsum, decay_log);
    k_chunk_scan<<<B_ * H_ * NC_, 128, 0, stream>>>(Ssum, zsum, decay_log);
    k_chunk_out<<<B_ * H_ * NC_, 256, 0, stream>>>(qb, kb, vb, gb, Ssum, zsum, ogb, decay_log);
    k_gemm_out<<<512, 256, 0, stream>>>(ogb, wob, y);
}